// Round 3
// baseline (892.926 us; speedup 1.0000x reference)
//
#include <hip/hip_runtime.h>
#include <hip/hip_bf16.h>

// VQ-VAE forward loss on MI355X.
// loss = 2.25 * mean((emb[argmin] - x)^2)
//      = 2.25/(N*D) * [ sum(x^2) + sum_n min_k(||e_k||^2 - 2 x_n.e_k) ]
//
// R5: spill fix. R4's WRITE_SIZE=164MB was scratch spill (staging regs + 64
// AGPR acc + B dbuf > 128-reg budget). Changes:
//  - x staged fp32 via global_load_lds into thread-private LDS scratch (tmp):
//    zero persistent staging VGPRs. Convert phase reads OWN slots (no barrier
//    needed for tmp; per-wave vmcnt(0) suffices), computes xsq, writes bf16 tile.
//  - raw "s_waitcnt lgkmcnt(0); s_barrier" instead of __syncthreads so the
//    next chunk's global_load_lds stays in flight across the barrier (T4).
//  - no array-indexed register buffers (rule #20): named Be*/Bo* B frags,
//    named acc00..acc11.
//  - keeps R4's verified 32x32x16 MFMA fragment/fold/reduction layout.

#define NROWS (64 * 4096)   // 262144
#define DDIM  480
#define KCODES 512
#define BM    64            // rows per block
#define BK    96            // k-chunk: 6 MFMA k-steps of 16
#define NCH   5             // 480 / 96
#define LDSP  104           // padded chunk row stride (bf16 elems)
#define NT    512           // threads per block (8 waves)

typedef __bf16 bf16x8 __attribute__((ext_vector_type(8)));
typedef float  f32x16 __attribute__((ext_vector_type(16)));

typedef const unsigned int __attribute__((address_space(1)))* as1_u32p;
typedef unsigned int __attribute__((address_space(3)))* as3_u32p;

__device__ __forceinline__ void async_cp16(const float* g, float* l) {
    __builtin_amdgcn_global_load_lds((as1_u32p)g, (as3_u32p)l, 16, 0, 0);
}

__device__ __forceinline__ ushort f2bf(float v) {
    union { float f; unsigned u; } c; c.f = v;
    unsigned u = c.u;
    u += 0x7fffu + ((u >> 16) & 1u);   // round-to-nearest-even
    return (ushort)(u >> 16);
}

// Convert codebook to bf16 in ws, compute ||e_k||^2 (fp32 exact), zero d_out.
__global__ void vq_setup(const float* __restrict__ e, ushort* __restrict__ ebf,
                         float* __restrict__ esq, float* __restrict__ out) {
    const int k = blockIdx.x;
    const int t = threadIdx.x;
    if (k == 0 && t == 0) out[0] = 0.0f;
    float s = 0.0f;
    for (int d = t; d < DDIM; d += 64) {
        float v = e[k * DDIM + d];
        s += v * v;
        ebf[k * DDIM + d] = f2bf(v);
    }
    #pragma unroll
    for (int m = 32; m >= 1; m >>= 1) s += __shfl_xor(s, m, 64);
    if (t == 0) esq[k] = s;
}

#define BARRIER() asm volatile("s_waitcnt lgkmcnt(0)\n\ts_barrier" ::: "memory")
#define WAITV0()  asm volatile("s_waitcnt vmcnt(0)" ::: "memory")

__global__ __launch_bounds__(NT, 4) void vq_main(const float* __restrict__ x,
        const ushort* __restrict__ ebf, const float* __restrict__ esq,
        float* __restrict__ out) {
    __shared__ ushort xs[2][BM * LDSP];   // 26624 B
    __shared__ float tmp[3 * NT * 4];     // 24576 B, thread-private fp32 slots
    __shared__ float red[8 * BM];         // 2048 B
    __shared__ float redw[8];

    const int t    = threadIdx.x;
    const int wave = t >> 6;
    const int lane = t & 63;
    const int l31  = lane & 31;   // 32x32 MFMA row/col lane index
    const int hw   = lane >> 5;   // k-half

    const float* xb = x + (size_t)blockIdx.x * (BM * DDIM);

    // staging map: chunk = 64 rows x 24 float4 = 1536 float4; 3 per thread
    const int r0 = t / 24,              c0 = (t % 24) * 4;
    const int r1 = (t + NT) / 24,       c1 = ((t + NT) % 24) * 4;
    const int r2 = (t + 2 * NT) / 24,   c2 = ((t + 2 * NT) % 24) * 4;
    const int go0 = r0 * DDIM + c0, go1 = r1 * DDIM + c1, go2 = r2 * DDIM + c2;
    const int lo0 = r0 * LDSP + c0, lo1 = r1 * LDSP + c1, lo2 = r2 * LDSP + c2;
    float* tp0 = &tmp[(0 * NT + t) * 4];
    float* tp1 = &tmp[(1 * NT + t) * 4];
    float* tp2 = &tmp[(2 * NT + t) * 4];

    float xsq = 0.0f;

#define STAGE_ISSUE(CH) do {                          \
        async_cp16(xb + go0 + (CH) * BK, tp0);        \
        async_cp16(xb + go1 + (CH) * BK, tp1);        \
        async_cp16(xb + go2 + (CH) * BK, tp2);        \
    } while (0)

#define CONVERT(NB) do {                                                    \
        float4 v0 = *(const float4*)tp0;                                    \
        float4 v1 = *(const float4*)tp1;                                    \
        float4 v2 = *(const float4*)tp2;                                    \
        xsq += v0.x * v0.x + v0.y * v0.y + v0.z * v0.z + v0.w * v0.w;       \
        xsq += v1.x * v1.x + v1.y * v1.y + v1.z * v1.z + v1.w * v1.w;       \
        xsq += v2.x * v2.x + v2.y * v2.y + v2.z * v2.z + v2.w * v2.w;       \
        ushort4 b;                                                          \
        b.x = f2bf(v0.x); b.y = f2bf(v0.y); b.z = f2bf(v0.z); b.w = f2bf(v0.w); \
        *(ushort4*)(&xs[NB][lo0]) = b;                                      \
        b.x = f2bf(v1.x); b.y = f2bf(v1.y); b.z = f2bf(v1.z); b.w = f2bf(v1.w); \
        *(ushort4*)(&xs[NB][lo1]) = b;                                      \
        b.x = f2bf(v2.x); b.y = f2bf(v2.y); b.z = f2bf(v2.z); b.w = f2bf(v2.w); \
        *(ushort4*)(&xs[NB][lo2]) = b;                                      \
    } while (0)

    // per-wave code slice: 64 codes = 2 coltiles of 32
    const int code0 = wave * 64;
    const ushort* bp0 = ebf + (size_t)(code0 + l31) * DDIM + hw * 8;
    const ushort* bp1 = bp0 + (size_t)32 * DDIM;

    f32x16 acc00, acc01, acc10, acc11;
    #pragma unroll
    for (int j = 0; j < 16; ++j) { acc00[j] = 0.f; acc01[j] = 0.f; acc10[j] = 0.f; acc11[j] = 0.f; }

    bf16x8 Be0, Be1, Bo0, Bo1;   // named double buffer (even/odd k-step)

    // ---- prologue ----
    STAGE_ISSUE(0);
    WAITV0();                 // chunk 0 fp32 landed (own-wave slots)
    CONVERT(0);
    STAGE_ISSUE(1);           // in flight across the barrier + chunk 0 compute
    Be0 = *(const bf16x8*)bp0;
    Be1 = *(const bf16x8*)bp1;
    BARRIER();

#define KSTEP(DK, KK, CUR, B0, B1, P0, P1) do {                              \
        if ((DK) < 29) {                                                     \
            P0 = *(const bf16x8*)(bp0 + ((DK) + 1) * 16);                    \
            P1 = *(const bf16x8*)(bp1 + ((DK) + 1) * 16);                    \
        }                                                                    \
        bf16x8 A0 = *(const bf16x8*)(&xs[CUR][l31 * LDSP + (KK) * 16 + hw * 8]);        \
        bf16x8 A1 = *(const bf16x8*)(&xs[CUR][(32 + l31) * LDSP + (KK) * 16 + hw * 8]); \
        acc00 = __builtin_amdgcn_mfma_f32_32x32x16_bf16(A0, B0, acc00, 0, 0, 0); \
        acc01 = __builtin_amdgcn_mfma_f32_32x32x16_bf16(A0, B1, acc01, 0, 0, 0); \
        acc10 = __builtin_amdgcn_mfma_f32_32x32x16_bf16(A1, B0, acc10, 0, 0, 0); \
        acc11 = __builtin_amdgcn_mfma_f32_32x32x16_bf16(A1, B1, acc11, 0, 0, 0); \
    } while (0)

    // ---- main pipeline: 5 chunks ----
    #pragma unroll
    for (int t5 = 0; t5 < NCH; ++t5) {
        const int cur = t5 & 1;
        KSTEP(t5 * 6 + 0, 0, cur, Be0, Be1, Bo0, Bo1);
        KSTEP(t5 * 6 + 1, 1, cur, Bo0, Bo1, Be0, Be1);
        KSTEP(t5 * 6 + 2, 2, cur, Be0, Be1, Bo0, Bo1);
        KSTEP(t5 * 6 + 3, 3, cur, Bo0, Bo1, Be0, Be1);
        KSTEP(t5 * 6 + 4, 4, cur, Be0, Be1, Bo0, Bo1);
        KSTEP(t5 * 6 + 5, 5, cur, Bo0, Bo1, Be0, Be1);
        if (t5 < NCH - 1) {
            WAITV0();               // drain chunk t5+1 fp32 (and B prefetch)
            CONVERT(cur ^ 1);
            if (t5 < NCH - 2) STAGE_ISSUE(t5 + 2);   // after convert freed tmp
        }
        BARRIER();                  // lgkm-only: gloads stay in flight
    }

    // ---- fold: min_k (esq[k] - 2*dot) ----
    // acc row = r*32 + (j&3) + 8*(j>>2) + 4*hw, col(code) = code0 + c*32 + l31
    const float es0 = esq[code0 + l31];
    const float es1 = esq[code0 + 32 + l31];
    float rm0[16], rm1[16];
    #pragma unroll
    for (int j = 0; j < 16; ++j) {
        rm0[j] = fminf(es0 - 2.0f * acc00[j], es1 - 2.0f * acc01[j]);
        rm1[j] = fminf(es0 - 2.0f * acc10[j], es1 - 2.0f * acc11[j]);
    }

    // cross-lane min over the 32 col lanes (bits 0..4, stays in half-wave)
    #pragma unroll
    for (int j = 0; j < 16; ++j) {
        float v = rm0[j];
        v = fminf(v, __shfl_xor(v, 1, 64));
        v = fminf(v, __shfl_xor(v, 2, 64));
        v = fminf(v, __shfl_xor(v, 4, 64));
        v = fminf(v, __shfl_xor(v, 8, 64));
        v = fminf(v, __shfl_xor(v, 16, 64));
        if (l31 == 0) red[wave * 64 + (j & 3) + 8 * (j >> 2) + 4 * hw] = v;
        float w2 = rm1[j];
        w2 = fminf(w2, __shfl_xor(w2, 1, 64));
        w2 = fminf(w2, __shfl_xor(w2, 2, 64));
        w2 = fminf(w2, __shfl_xor(w2, 4, 64));
        w2 = fminf(w2, __shfl_xor(w2, 8, 64));
        w2 = fminf(w2, __shfl_xor(w2, 16, 64));
        if (l31 == 0) red[wave * 64 + 32 + (j & 3) + 8 * (j >> 2) + 4 * hw] = w2;
    }
    __syncthreads();

    // ---- combine: min across 8 waves per row, + sum(x^2), block reduce ----
    float val = xsq;
    if (t < 64) {
        float m0 = fminf(red[t],       red[64 + t]);
        float m1 = fminf(red[128 + t], red[192 + t]);
        float m2 = fminf(red[256 + t], red[320 + t]);
        float m3 = fminf(red[384 + t], red[448 + t]);
        val += fminf(fminf(m0, m1), fminf(m2, m3));
    }
    #pragma unroll
    for (int m = 32; m >= 1; m >>= 1) val += __shfl_xor(val, m, 64);
    if (lane == 0) redw[wave] = val;
    __syncthreads();
    if (t == 0) {
        const float SCALE = 2.25f / ((float)NROWS * (float)DDIM);
        float s = 0.f;
        #pragma unroll
        for (int w = 0; w < 8; ++w) s += redw[w];
        atomicAdd(out, s * SCALE);
    }
}

extern "C" void kernel_launch(void* const* d_in, const int* in_sizes, int n_in,
                              void* d_out, int out_size, void* d_ws, size_t ws_size,
                              hipStream_t stream) {
    (void)in_sizes; (void)n_in; (void)out_size; (void)ws_size;
    const float* x = (const float*)d_in[0];   // [262144, 480] fp32
    const float* e = (const float*)d_in[1];   // [512, 480] fp32
    float* out = (float*)d_out;               // scalar fp32
    ushort* ebf = (ushort*)d_ws;                              // 512*480*2 = 491520 B
    float*  esq = (float*)((char*)d_ws + KCODES * DDIM * 2);  // 512*4 B

    vq_setup<<<KCODES, 64, 0, stream>>>(e, ebf, esq, out);
    vq_main<<<NROWS / BM, NT, 0, stream>>>(x, ebf, esq, out);
}